// Round 3
// baseline (13533.122 us; speedup 1.0000x reference)
//
#include <hip/hip_runtime.h>
#include <math.h>

// Problem dims (fixed by reference)
#define SEQ   128
#define BATCH 64
#define HD    1024
#define NG    4096
#define TOUT  32
#define NB    256      // blocks (== CU count, 1/CU; cooperative co-resident)
#define NT    256      // threads per block (4 waves)
#define NE    65536    // BATCH*HD

typedef __attribute__((ext_vector_type(8))) short short8;
typedef __attribute__((ext_vector_type(4))) float f32x4;

__device__ inline ushort bf16_rne(float x) {
    union { float f; unsigned u; } v; v.f = x;
    unsigned r = v.u + 0x7FFF + ((v.u >> 16) & 1);
    return (ushort)(r >> 16);
}

// fp32 -> bf16 (RNE), 4 elems/thread; n % 1024 == 0. First block optionally
// zeroes the grid-barrier words (must happen every launch: ws is re-poisoned).
__global__ __launch_bounds__(256) void cvt_bf16(
    const float* __restrict__ src, ushort* __restrict__ dst, int n,
    unsigned* bar)
{
    if (bar && blockIdx.x == 0 && threadIdx.x < 2) bar[threadIdx.x] = 0u;
    int i = (blockIdx.x * 256 + threadIdx.x) * 4;
    if (i < n) {
        float4 v = *(const float4*)(src + i);
        ushort4 o;
        o.x = bf16_rne(v.x); o.y = bf16_rne(v.y);
        o.z = bf16_rne(v.z); o.w = bf16_rne(v.w);
        *(ushort4*)(dst + i) = o;
    }
}

// Device-scope grid barrier (cooperative launch guarantees co-residency).
// bar[0] = arrive count, bar[1] = generation.
__device__ inline void grid_sync(unsigned* bar) {
    __threadfence();            // release: publish this block's stores
    __syncthreads();
    if (threadIdx.x == 0) {
        unsigned g = __hip_atomic_load(bar + 1, __ATOMIC_RELAXED, __HIP_MEMORY_SCOPE_AGENT);
        unsigned a = __hip_atomic_fetch_add(bar, 1u, __ATOMIC_ACQ_REL, __HIP_MEMORY_SCOPE_AGENT);
        if (a == gridDim.x - 1) {
            __hip_atomic_store(bar, 0u, __ATOMIC_RELAXED, __HIP_MEMORY_SCOPE_AGENT);
            __hip_atomic_fetch_add(bar + 1, 1u, __ATOMIC_RELEASE, __HIP_MEMORY_SCOPE_AGENT);
        } else {
            while (__hip_atomic_load(bar + 1, __ATOMIC_RELAXED, __HIP_MEMORY_SCOPE_AGENT) == g) {
                __builtin_amdgcn_s_sleep(1);
            }
        }
    }
    __syncthreads();
    __threadfence();            // acquire: invalidate stale cache lines
}

// ---------------------------------------------------------------------------
// Persistent fused LSTM. Block b owns hidden units [4b, 4b+4) -> 16 gate rows
// (4 units x 4 types, col c = type*4 + u). Weights read from global bf16 (L2).
// Per cell step: gates = x@W_ih^T + h@W_hh^T via MFMA (A-frags from global,
// B-frags from global), pointwise via 4KB LDS tile, c in a register.
// Blocks 0..63 additionally run proj (16 out-cols each) and softmax (1 batch
// row each) during decode.
// ---------------------------------------------------------------------------
__global__ __launch_bounds__(256) void lstm_mega(
    const ushort* __restrict__ Wih, const ushort* __restrict__ Whh,
    const ushort* __restrict__ Wout, const ushort* __restrict__ Xbf,
    ushort* __restrict__ h0b, ushort* __restrict__ h1b,
    ushort* __restrict__ xd, float* __restrict__ y, unsigned* bar,
    const float* __restrict__ b_ih, const float* __restrict__ b_hh,
    const float* __restrict__ b_out, const float* __restrict__ c0,
    float* __restrict__ out)
{
    __shared__ float gbuf[64 * 17];   // gate tile [batch][col], pad 17
    __shared__ float red_s[256];
    __shared__ float bsum_s[16];
    __shared__ float bout_s[16];

    const int tid  = threadIdx.x;
    const int blk  = blockIdx.x;
    const int wave = tid >> 6;
    const int lane = tid & 63;
    const int l15  = lane & 15;
    const int q8   = (lane >> 4) * 8;
    const int r0   = (lane >> 4) * 4;
    const int j0   = blk * 4;            // first owned hidden unit
    const int pb   = tid >> 2;           // pointwise batch row
    const int pu   = tid & 3;            // pointwise unit

    if (tid < 16) {
        int type = tid >> 2, u = tid & 3;
        int row = type * 1024 + j0 + u;
        bsum_s[tid] = b_ih[row] + b_hh[row];
        if (blk < 64) bout_s[tid] = b_out[blk * 16 + tid];
    }
    float c_reg = c0[pb * 1024 + j0 + pu];

    // B-fragment row for lane: col c = l15 -> W row = (c>>2)*1024 + j0 + (c&3)
    const int brow = (l15 >> 2) * 1024 + j0 + (l15 & 3);
    const ushort* bp_ih  = Wih + (size_t)brow * 1024 + q8;
    const ushort* bp_hh  = Whh + (size_t)brow * 1024 + q8;
    const ushort* bp_out = Wout + (size_t)((blk < 64 ? blk * 16 + l15 : 0)) * 1024 + q8;

    const int arow_off = (wave * 16 + l15) * 1024 + q8;
    __syncthreads();

    ushort* cur = h0b;
    ushort* nxt = h1b;

    auto cell_step = [&](const ushort* __restrict__ xsrc,
                         const ushort* __restrict__ hcur,
                         ushort* __restrict__ hnxt, bool fin) {
        const ushort* ax_p = xsrc + arow_off;
        const ushort* ah_p = hcur + arow_off;
        f32x4 acc = {0.f, 0.f, 0.f, 0.f};
        #pragma unroll 8
        for (int kk = 0; kk < 1024; kk += 32) {
            short8 ax = *(const short8*)(ax_p + kk);
            short8 ah = *(const short8*)(ah_p + kk);
            short8 bi = *(const short8*)(bp_ih + kk);
            short8 bh = *(const short8*)(bp_hh + kk);
            acc = __builtin_amdgcn_mfma_f32_16x16x32_bf16(ax, bi, acc, 0, 0, 0);
            acc = __builtin_amdgcn_mfma_f32_16x16x32_bf16(ah, bh, acc, 0, 0, 0);
        }
        #pragma unroll
        for (int r = 0; r < 4; r++)
            gbuf[(wave * 16 + r0 + r) * 17 + l15] = acc[r];
        __syncthreads();
        float ig = gbuf[pb * 17 + pu]      + bsum_s[pu];
        float fg = gbuf[pb * 17 + 4 + pu]  + bsum_s[4 + pu];
        float gg = gbuf[pb * 17 + 8 + pu]  + bsum_s[8 + pu];
        float og = gbuf[pb * 17 + 12 + pu] + bsum_s[12 + pu];
        float si = 1.f / (1.f + expf(-ig));
        float sf = 1.f / (1.f + expf(-fg));
        float so = 1.f / (1.f + expf(-og));
        float tg = tanhf(gg);
        float cn = sf * c_reg + si * tg;
        c_reg = cn;
        float hn = so * tanhf(cn);
        hnxt[pb * 1024 + j0 + pu] = bf16_rne(hn);
        if (fin) {
            out[(size_t)TOUT * NE + pb * 1024 + j0 + pu]       = hn;
            out[(size_t)(TOUT + 1) * NE + pb * 1024 + j0 + pu] = cn;
        }
    };

    auto proj_step = [&](const ushort* __restrict__ hcur) {
        if (blk < 64) {
            const ushort* ah_p = hcur + arow_off;
            f32x4 acc = {0.f, 0.f, 0.f, 0.f};
            #pragma unroll 8
            for (int kk = 0; kk < 1024; kk += 32) {
                short8 a = *(const short8*)(ah_p + kk);
                short8 b = *(const short8*)(bp_out + kk);
                acc = __builtin_amdgcn_mfma_f32_16x16x32_bf16(a, b, acc, 0, 0, 0);
            }
            #pragma unroll
            for (int r = 0; r < 4; r++)
                y[(size_t)(wave * 16 + r0 + r) * 1024 + blk * 16 + l15] = acc[r] + bout_s[l15];
        }
    };

    auto softmax_step = [&](float* __restrict__ outp) {
        if (blk < 64) {
            const float* row = y + blk * 1024;
            float4 v = *(const float4*)(row + tid * 4);
            red_s[tid] = fmaxf(fmaxf(v.x, v.y), fmaxf(v.z, v.w));
            __syncthreads();
            for (int st = 128; st > 0; st >>= 1) {
                if (tid < st) red_s[tid] = fmaxf(red_s[tid], red_s[tid + st]);
                __syncthreads();
            }
            float m = red_s[0];
            __syncthreads();
            red_s[tid] = expf(v.x - m) + expf(v.y - m) + expf(v.z - m) + expf(v.w - m);
            __syncthreads();
            for (int st = 128; st > 0; st >>= 1) {
                if (tid < st) red_s[tid] += red_s[tid + st];
                __syncthreads();
            }
            float lse = m + logf(red_s[0]);
            float4 o = make_float4(v.x - lse, v.y - lse, v.z - lse, v.w - lse);
            *(float4*)(outp + blk * 1024 + tid * 4) = o;
            ushort4 xo = make_ushort4(bf16_rne(o.x), bf16_rne(o.y),
                                      bf16_rne(o.z), bf16_rne(o.w));
            *(ushort4*)(xd + blk * 1024 + tid * 4) = xo;
        }
    };

    // ---- encode ----
    for (int t = 0; t < SEQ; t++) {
        cell_step(Xbf + (size_t)t * NE, cur, nxt, false);
        grid_sync(bar);
        ushort* tmp = cur; cur = nxt; nxt = tmp;
    }

    // ---- out0 ----
    proj_step(cur);
    grid_sync(bar);
    softmax_step(out);
    grid_sync(bar);

    // ---- decode ----
    for (int d = 1; d < TOUT; d++) {
        cell_step(xd, cur, nxt, d == TOUT - 1);
        grid_sync(bar);
        ushort* tmp = cur; cur = nxt; nxt = tmp;
        proj_step(cur);
        grid_sync(bar);
        softmax_step(out + (size_t)d * NE);
        grid_sync(bar);
    }
}

// ---------------------------------------------------------------------------
extern "C" void kernel_launch(void* const* d_in, const int* in_sizes, int n_in,
                              void* d_out, int out_size, void* d_ws, size_t ws_size,
                              hipStream_t stream)
{
    const float* input = (const float*)d_in[0];   // [128,64,1024]
    const float* h0    = (const float*)d_in[1];
    const float* c0    = (const float*)d_in[2];
    const float* W_ih  = (const float*)d_in[3];   // [4096,1024]
    const float* W_hh  = (const float*)d_in[4];
    const float* b_ih  = (const float*)d_in[5];
    const float* b_hh  = (const float*)d_in[6];
    const float* W_out = (const float*)d_in[7];   // [1024,1024]
    const float* b_out = (const float*)d_in[8];
    float* out = (float*)d_out;                   // [32,64,1024] + h + c

    char* w = (char*)d_ws;
    ushort*   Wih_bf  = (ushort*)(w + 0);          //  8,388,608 B
    ushort*   Whh_bf  = (ushort*)(w + 8388608);    //  8,388,608 B
    ushort*   Wout_bf = (ushort*)(w + 16777216);   //  2,097,152 B
    ushort*   Xbf     = (ushort*)(w + 18874368);   // 16,777,216 B
    ushort*   h0b     = (ushort*)(w + 35651584);   //    131,072 B
    ushort*   h1b     = (ushort*)(w + 35782656);   //    131,072 B
    ushort*   xd      = (ushort*)(w + 35913728);   //    131,072 B
    float*    y       = (float*) (w + 36044800);   //    262,144 B
    unsigned* bar     = (unsigned*)(w + 36306944); //        128 B

    // one-time converts (first also zeroes the barrier)
    cvt_bf16<<<dim3(4096), dim3(256), 0, stream>>>(W_ih,  Wih_bf,  NG * HD, bar);
    cvt_bf16<<<dim3(4096), dim3(256), 0, stream>>>(W_hh,  Whh_bf,  NG * HD, nullptr);
    cvt_bf16<<<dim3(1024), dim3(256), 0, stream>>>(W_out, Wout_bf, HD * HD, nullptr);
    cvt_bf16<<<dim3(8192), dim3(256), 0, stream>>>(input, Xbf, SEQ * NE, nullptr);
    cvt_bf16<<<dim3(64),   dim3(256), 0, stream>>>(h0,    h0b, NE, nullptr);

    const ushort* a0 = Wih_bf;  const ushort* a1 = Whh_bf;
    const ushort* a2 = Wout_bf; const ushort* a3 = Xbf;
    ushort* a4 = h0b; ushort* a5 = h1b; ushort* a6 = xd;
    float* a7 = y; unsigned* a8 = bar;
    const float* a9 = b_ih; const float* a10 = b_hh; const float* a11 = b_out;
    const float* a12 = c0;  float* a13 = out;
    void* args[] = {&a0, &a1, &a2, &a3, &a4, &a5, &a6, &a7, &a8,
                    &a9, &a10, &a11, &a12, &a13};
    hipLaunchCooperativeKernel((const void*)lstm_mega, dim3(NB), dim3(NT),
                               args, 0, stream);
}

// Round 4
// 3183.134 us; speedup vs baseline: 4.2515x; 4.2515x over previous
//
#include <hip/hip_runtime.h>
#include <math.h>

// Problem dims (fixed by reference)
#define SEQ   128
#define BATCH 64
#define HD    1024
#define NG    4096
#define TOUT  32
#define NE    65536    // BATCH*HD
#define CHS   16       // encode steps per hoisted-Xg chunk

typedef __attribute__((ext_vector_type(8))) short short8;
typedef __attribute__((ext_vector_type(4))) float f32x4;

__device__ inline ushort bf16_rne(float x) {
    union { float f; unsigned u; } v; v.f = x;
    unsigned r = v.u + 0x7FFF + ((v.u >> 16) & 1);
    return (ushort)(r >> 16);
}

// ---------------------------------------------------------------------------
// fp32 -> bf16 (RNE), 4 elems/thread; n % 1024 == 0
// ---------------------------------------------------------------------------
__global__ __launch_bounds__(256) void cvt_bf16(
    const float* __restrict__ src, ushort* __restrict__ dst, int n)
{
    int i = (blockIdx.x * 256 + threadIdx.x) * 4;
    if (i < n) {
        float4 v = *(const float4*)(src + i);
        ushort4 o;
        o.x = bf16_rne(v.x); o.y = bf16_rne(v.y);
        o.z = bf16_rne(v.z); o.w = bf16_rne(v.w);
        *(ushort4*)(dst + i) = o;
    }
}

// ---------------------------------------------------------------------------
// prep: h_bf = bf16(h0); cbuf = c0; bsum = b_ih + b_hh.  grid 256 x 256.
// ---------------------------------------------------------------------------
__global__ __launch_bounds__(256) void prep(
    const float* __restrict__ h0, const float* __restrict__ c0,
    const float* __restrict__ b_ih, const float* __restrict__ b_hh,
    ushort* __restrict__ h_bf, float* __restrict__ cbuf, float* __restrict__ bsum)
{
    int idx = blockIdx.x * 256 + threadIdx.x;
    h_bf[idx] = bf16_rne(h0[idx]);
    cbuf[idx] = c0[idx];
    if (idx < NG) bsum[idx] = b_ih[idx] + b_hh[idx];
}

// ---------------------------------------------------------------------------
// Xg chunk GEMM: C[1024][4096] = A[1024][1024] @ B[4096][1024]^T  (bf16->fp32)
// grid (4096/64, 1024/64) = (64,16), block 256.  LDS-free direct MFMA frags.
// ---------------------------------------------------------------------------
__global__ __launch_bounds__(256) void gemm_xg(
    const ushort* __restrict__ A, const ushort* __restrict__ B, float* __restrict__ C)
{
    const int wave = threadIdx.x >> 6, lane = threadIdx.x & 63;
    const int l15 = lane & 15, q8 = (lane >> 4) * 8, r0 = (lane >> 4) * 4;
    const int mrow = blockIdx.y * 64 + wave * 16 + l15;
    const int nbase = blockIdx.x * 64;

    const ushort* ap  = A + (size_t)mrow * 1024 + q8;
    const ushort* bp0 = B + (size_t)(nbase + l15) * 1024 + q8;
    const ushort* bp1 = bp0 + 16 * 1024;
    const ushort* bp2 = bp0 + 32 * 1024;
    const ushort* bp3 = bp0 + 48 * 1024;

    f32x4 acc0 = {0,0,0,0}, acc1 = {0,0,0,0}, acc2 = {0,0,0,0}, acc3 = {0,0,0,0};
    #pragma unroll 8
    for (int kk = 0; kk < 1024; kk += 32) {
        short8 a  = *(const short8*)(ap + kk);
        short8 b0 = *(const short8*)(bp0 + kk);
        short8 b1 = *(const short8*)(bp1 + kk);
        short8 b2 = *(const short8*)(bp2 + kk);
        short8 b3 = *(const short8*)(bp3 + kk);
        acc0 = __builtin_amdgcn_mfma_f32_16x16x32_bf16(a, b0, acc0, 0, 0, 0);
        acc1 = __builtin_amdgcn_mfma_f32_16x16x32_bf16(a, b1, acc1, 0, 0, 0);
        acc2 = __builtin_amdgcn_mfma_f32_16x16x32_bf16(a, b2, acc2, 0, 0, 0);
        acc3 = __builtin_amdgcn_mfma_f32_16x16x32_bf16(a, b3, acc3, 0, 0, 0);
    }
    const int rbase = blockIdx.y * 64 + wave * 16 + r0;
    #pragma unroll
    for (int r = 0; r < 4; r++) {
        float* cp = C + (size_t)(rbase + r) * NG + nbase + l15;
        cp[0]  = acc0[r];
        cp[16] = acc1[r];
        cp[32] = acc2[r];
        cp[48] = acc3[r];
    }
}

// ---------------------------------------------------------------------------
// Encode cell: block b owns units [4b,4b+4) -> 16 gate cols (c = type*4+u).
// gates = (precomputed xg) + h@W_hh^T + bias; pointwise; h' bf16 out.
// grid 256 x 256.  1 MFMA/wave/k-iter (2 interleaved acc chains).
// ---------------------------------------------------------------------------
__global__ __launch_bounds__(256) void cell_enc(
    const float* __restrict__ xg,          // [64][4096] this step's slice
    const ushort* __restrict__ hcur, const ushort* __restrict__ Whh,
    const float* __restrict__ bsum, float* __restrict__ cbuf,
    ushort* __restrict__ hnxt)
{
    __shared__ float gbuf[64 * 17];
    const int tid = threadIdx.x, blk = blockIdx.x;
    const int wave = tid >> 6, lane = tid & 63;
    const int l15 = lane & 15, q8 = (lane >> 4) * 8, r0 = (lane >> 4) * 4;
    const int j0 = blk * 4;
    const int brow = (l15 >> 2) * 1024 + j0 + (l15 & 3);

    const ushort* ap = hcur + (size_t)(wave * 16 + l15) * 1024 + q8;
    const ushort* bp = Whh + (size_t)brow * 1024 + q8;

    f32x4 a0 = {0,0,0,0}, a1 = {0,0,0,0};
    #pragma unroll 8
    for (int kk = 0; kk < 1024; kk += 64) {
        short8 h0v = *(const short8*)(ap + kk);
        short8 w0v = *(const short8*)(bp + kk);
        short8 h1v = *(const short8*)(ap + kk + 32);
        short8 w1v = *(const short8*)(bp + kk + 32);
        a0 = __builtin_amdgcn_mfma_f32_16x16x32_bf16(h0v, w0v, a0, 0, 0, 0);
        a1 = __builtin_amdgcn_mfma_f32_16x16x32_bf16(h1v, w1v, a1, 0, 0, 0);
    }
    f32x4 acc = a0 + a1;
    #pragma unroll
    for (int r = 0; r < 4; r++)
        gbuf[(wave * 16 + r0 + r) * 17 + l15] = acc[r];
    __syncthreads();

    const int pb = tid >> 2, pu = tid & 3;
    float ig = gbuf[pb * 17 + pu]      + xg[(size_t)pb * NG + j0 + pu]        + bsum[j0 + pu];
    float fg = gbuf[pb * 17 + 4 + pu]  + xg[(size_t)pb * NG + 1024 + j0 + pu] + bsum[1024 + j0 + pu];
    float gg = gbuf[pb * 17 + 8 + pu]  + xg[(size_t)pb * NG + 2048 + j0 + pu] + bsum[2048 + j0 + pu];
    float og = gbuf[pb * 17 + 12 + pu] + xg[(size_t)pb * NG + 3072 + j0 + pu] + bsum[3072 + j0 + pu];
    float si = 1.f / (1.f + expf(-ig));
    float sf = 1.f / (1.f + expf(-fg));
    float so = 1.f / (1.f + expf(-og));
    float tg = tanhf(gg);
    const int ci = pb * 1024 + j0 + pu;
    float cn = sf * cbuf[ci] + si * tg;
    cbuf[ci] = cn;
    hnxt[ci] = bf16_rne(so * tanhf(cn));
}

// ---------------------------------------------------------------------------
// Decode cell: gates = x@W_ih^T + h@W_hh^T + bias (4 acc chains, 2 MFMA/iter).
// If finout != null, also writes fp32 h (finout[0..NE)) and c (finout[NE..2NE)).
// ---------------------------------------------------------------------------
__global__ __launch_bounds__(256) void cell_dec(
    const ushort* __restrict__ xbf, const ushort* __restrict__ hcur,
    const ushort* __restrict__ Wih, const ushort* __restrict__ Whh,
    const float* __restrict__ bsum, float* __restrict__ cbuf,
    ushort* __restrict__ hnxt, float* __restrict__ finout)
{
    __shared__ float gbuf[64 * 17];
    const int tid = threadIdx.x, blk = blockIdx.x;
    const int wave = tid >> 6, lane = tid & 63;
    const int l15 = lane & 15, q8 = (lane >> 4) * 8, r0 = (lane >> 4) * 4;
    const int j0 = blk * 4;
    const int brow = (l15 >> 2) * 1024 + j0 + (l15 & 3);
    const size_t aoff = (size_t)(wave * 16 + l15) * 1024 + q8;

    const ushort* axp = xbf + aoff;
    const ushort* ahp = hcur + aoff;
    const ushort* bip = Wih + (size_t)brow * 1024 + q8;
    const ushort* bhp = Whh + (size_t)brow * 1024 + q8;

    f32x4 x0 = {0,0,0,0}, x1 = {0,0,0,0}, h0a = {0,0,0,0}, h1a = {0,0,0,0};
    #pragma unroll 8
    for (int kk = 0; kk < 1024; kk += 64) {
        short8 ax0 = *(const short8*)(axp + kk);
        short8 bi0 = *(const short8*)(bip + kk);
        short8 ah0 = *(const short8*)(ahp + kk);
        short8 bh0 = *(const short8*)(bhp + kk);
        short8 ax1 = *(const short8*)(axp + kk + 32);
        short8 bi1 = *(const short8*)(bip + kk + 32);
        short8 ah1 = *(const short8*)(ahp + kk + 32);
        short8 bh1 = *(const short8*)(bhp + kk + 32);
        x0  = __builtin_amdgcn_mfma_f32_16x16x32_bf16(ax0, bi0, x0, 0, 0, 0);
        h0a = __builtin_amdgcn_mfma_f32_16x16x32_bf16(ah0, bh0, h0a, 0, 0, 0);
        x1  = __builtin_amdgcn_mfma_f32_16x16x32_bf16(ax1, bi1, x1, 0, 0, 0);
        h1a = __builtin_amdgcn_mfma_f32_16x16x32_bf16(ah1, bh1, h1a, 0, 0, 0);
    }
    f32x4 acc = (x0 + x1) + (h0a + h1a);
    #pragma unroll
    for (int r = 0; r < 4; r++)
        gbuf[(wave * 16 + r0 + r) * 17 + l15] = acc[r];
    __syncthreads();

    const int pb = tid >> 2, pu = tid & 3;
    float ig = gbuf[pb * 17 + pu]      + bsum[j0 + pu];
    float fg = gbuf[pb * 17 + 4 + pu]  + bsum[1024 + j0 + pu];
    float gg = gbuf[pb * 17 + 8 + pu]  + bsum[2048 + j0 + pu];
    float og = gbuf[pb * 17 + 12 + pu] + bsum[3072 + j0 + pu];
    float si = 1.f / (1.f + expf(-ig));
    float sf = 1.f / (1.f + expf(-fg));
    float so = 1.f / (1.f + expf(-og));
    float tg = tanhf(gg);
    const int ci = pb * 1024 + j0 + pu;
    float cn = sf * cbuf[ci] + si * tg;
    cbuf[ci] = cn;
    float hn = so * tanhf(cn);
    hnxt[ci] = bf16_rne(hn);
    if (finout) {
        finout[ci]      = hn;
        finout[NE + ci] = cn;
    }
}

// ---------------------------------------------------------------------------
// Projection: y[64][1024] = h@W_out^T + b_out.  Block = 16-col group; grid 64.
// ---------------------------------------------------------------------------
__global__ __launch_bounds__(256) void proj(
    const ushort* __restrict__ hcur, const ushort* __restrict__ Wout,
    const float* __restrict__ b_out, float* __restrict__ y)
{
    const int tid = threadIdx.x, blk = blockIdx.x;
    const int wave = tid >> 6, lane = tid & 63;
    const int l15 = lane & 15, q8 = (lane >> 4) * 8, r0 = (lane >> 4) * 4;
    const int j0p = blk * 16;

    const ushort* ap = hcur + (size_t)(wave * 16 + l15) * 1024 + q8;
    const ushort* bp = Wout + (size_t)(j0p + l15) * 1024 + q8;

    f32x4 a0 = {0,0,0,0}, a1 = {0,0,0,0};
    #pragma unroll 8
    for (int kk = 0; kk < 1024; kk += 64) {
        short8 h0v = *(const short8*)(ap + kk);
        short8 w0v = *(const short8*)(bp + kk);
        short8 h1v = *(const short8*)(ap + kk + 32);
        short8 w1v = *(const short8*)(bp + kk + 32);
        a0 = __builtin_amdgcn_mfma_f32_16x16x32_bf16(h0v, w0v, a0, 0, 0, 0);
        a1 = __builtin_amdgcn_mfma_f32_16x16x32_bf16(h1v, w1v, a1, 0, 0, 0);
    }
    f32x4 acc = a0 + a1;
    const float bo = b_out[j0p + l15];
    #pragma unroll
    for (int r = 0; r < 4; r++)
        y[(size_t)(wave * 16 + r0 + r) * 1024 + j0p + l15] = acc[r] + bo;
}

// ---------------------------------------------------------------------------
// Row log-softmax: block = batch row; writes fp32 out + bf16 next-input.
// ---------------------------------------------------------------------------
__global__ __launch_bounds__(256) void softmax_k(
    const float* __restrict__ y, float* __restrict__ outp, ushort* __restrict__ xd)
{
    __shared__ float red_s[256];
    const int tid = threadIdx.x, blk = blockIdx.x;
    const float* row = y + blk * 1024;
    float4 v = *(const float4*)(row + tid * 4);
    red_s[tid] = fmaxf(fmaxf(v.x, v.y), fmaxf(v.z, v.w));
    __syncthreads();
    for (int st = 128; st > 0; st >>= 1) {
        if (tid < st) red_s[tid] = fmaxf(red_s[tid], red_s[tid + st]);
        __syncthreads();
    }
    float m = red_s[0];
    __syncthreads();
    red_s[tid] = expf(v.x - m) + expf(v.y - m) + expf(v.z - m) + expf(v.w - m);
    __syncthreads();
    for (int st = 128; st > 0; st >>= 1) {
        if (tid < st) red_s[tid] += red_s[tid + st];
        __syncthreads();
    }
    float lse = m + logf(red_s[0]);
    float4 o = make_float4(v.x - lse, v.y - lse, v.z - lse, v.w - lse);
    *(float4*)(outp + blk * 1024 + tid * 4) = o;
    ushort4 xo = make_ushort4(bf16_rne(o.x), bf16_rne(o.y), bf16_rne(o.z), bf16_rne(o.w));
    *(ushort4*)(xd + blk * 1024 + tid * 4) = xo;
}

// ---------------------------------------------------------------------------
extern "C" void kernel_launch(void* const* d_in, const int* in_sizes, int n_in,
                              void* d_out, int out_size, void* d_ws, size_t ws_size,
                              hipStream_t stream)
{
    const float* input = (const float*)d_in[0];   // [128,64,1024]
    const float* h0    = (const float*)d_in[1];
    const float* c0    = (const float*)d_in[2];
    const float* W_ih  = (const float*)d_in[3];   // [4096,1024]
    const float* W_hh  = (const float*)d_in[4];
    const float* b_ih  = (const float*)d_in[5];
    const float* b_hh  = (const float*)d_in[6];
    const float* W_out = (const float*)d_in[7];   // [1024,1024]
    const float* b_out = (const float*)d_in[8];
    float* out = (float*)d_out;                   // [32,64,1024] + h + c

    char* w = (char*)d_ws;
    ushort* Wih_bf  = (ushort*)(w + 0);           //  8,388,608 B
    ushort* Whh_bf  = (ushort*)(w + 8388608);     //  8,388,608 B
    ushort* Wout_bf = (ushort*)(w + 16777216);    //  2,097,152 B
    ushort* Xbf     = (ushort*)(w + 18874368);    // 16,777,216 B
    float*  Xg      = (float*) (w + 35651584);    // 16,777,216 B (CHS chunk)
    float*  y       = (float*) (w + 52428800);    //    262,144 B
    ushort* h0b     = (ushort*)(w + 52690944);    //    131,072 B
    ushort* h1b     = (ushort*)(w + 52822016);    //    131,072 B
    ushort* xd      = (ushort*)(w + 52953088);    //    131,072 B
    float*  cbuf    = (float*) (w + 53084160);    //    262,144 B
    float*  bsum    = (float*) (w + 53346304);    //     16,384 B

    // one-time converts + state init
    cvt_bf16<<<dim3(4096), dim3(256), 0, stream>>>(W_ih,  Wih_bf,  NG * HD);
    cvt_bf16<<<dim3(4096), dim3(256), 0, stream>>>(W_hh,  Whh_bf,  NG * HD);
    cvt_bf16<<<dim3(1024), dim3(256), 0, stream>>>(W_out, Wout_bf, HD * HD);
    cvt_bf16<<<dim3(8192), dim3(256), 0, stream>>>(input, Xbf, SEQ * NE);
    prep<<<dim3(256), dim3(256), 0, stream>>>(h0, c0, b_ih, b_hh, h0b, cbuf, bsum);

    ushort* cur = h0b;
    ushort* nxt = h1b;

    // ---- encode: hoisted x@W_ih^T per 16-step chunk, then fused cell/step ----
    for (int ch = 0; ch < SEQ / CHS; ch++) {
        gemm_xg<<<dim3(NG / 64, (CHS * BATCH) / 64), dim3(256), 0, stream>>>(
            Xbf + (size_t)ch * CHS * NE, Wih_bf, Xg);
        for (int s = 0; s < CHS; s++) {
            cell_enc<<<dim3(256), dim3(256), 0, stream>>>(
                Xg + (size_t)s * BATCH * NG, cur, Whh_bf, bsum, cbuf, nxt);
            ushort* t = cur; cur = nxt; nxt = t;
        }
    }

    // ---- out0 ----
    proj<<<dim3(64), dim3(256), 0, stream>>>(cur, Wout_bf, b_out, y);
    softmax_k<<<dim3(64), dim3(256), 0, stream>>>(y, out, xd);

    // ---- decode ----
    for (int d = 1; d < TOUT; d++) {
        cell_dec<<<dim3(256), dim3(256), 0, stream>>>(
            xd, cur, Wih_bf, Whh_bf, bsum, cbuf, nxt,
            (d == TOUT - 1) ? (out + (size_t)TOUT * NE) : nullptr);
        ushort* t = cur; cur = nxt; nxt = t;
        proj<<<dim3(64), dim3(256), 0, stream>>>(cur, Wout_bf, b_out, y);
        softmax_k<<<dim3(64), dim3(256), 0, stream>>>(y, out + (size_t)d * NE, xd);
    }
}